// Round 12
// baseline (1349.161 us; speedup 1.0000x reference)
//
#include <hip/hip_runtime.h>

#define CIN    32
#define COUT   32
#define CH     256          // output rows per chunk (must be 256: code uses >>8, &255)
#define SCAN_B 2048

typedef _Float16 f16x8 __attribute__((ext_vector_type(8)));
typedef float    f32x4 __attribute__((ext_vector_type(4)));

__device__ __forceinline__ unsigned f2h2(float a, float b)
{
    unsigned short ua = __builtin_bit_cast(unsigned short, (_Float16)a);
    unsigned short ub = __builtin_bit_cast(unsigned short, (_Float16)b);
    return (unsigned)ua | ((unsigned)ub << 16);
}

// ---- prep: pack W into MFMA B-fragments, feat into f16 pairs, and histogram ----
// wFrag[((k*2+half)*64 + lane)*4 + v] = f16pair( W[k][(lane>>4)*8+2v][16*half+(lane&15)],
//                                               W[k][(lane>>4)*8+2v+1][same o] )
// fH[g*16 + c] = f16pair(feat[g][2c], feat[g][2c+1])
// cnt[(s>>8)*K + k] += 1 for valid pairs
__global__ void k_prep2(const float* __restrict__ w, const float* __restrict__ f,
                        const int* __restrict__ scatter,
                        unsigned* __restrict__ wFrag, unsigned* __restrict__ fH,
                        int* __restrict__ cnt,
                        int K, int N, int npair, int M, int vec_ok)
{
    const int t0 = blockIdx.x * blockDim.x + threadIdx.x;
    const int stride = gridDim.x * blockDim.x;

    const int wtot = K * 512;
    for (int i = t0; i < wtot; i += stride) {
        int v = i & 3, lane = (i >> 2) & 63, half = (i >> 8) & 1, k = i >> 9;
        int i0 = (lane >> 4) * 8 + 2 * v;
        int o  = half * 16 + (lane & 15);
        wFrag[i] = f2h2(w[(k * CIN + i0) * COUT + o], w[(k * CIN + i0 + 1) * COUT + o]);
    }
    for (int i = t0; i < N * 8; i += stride) {
        float4 v = ((const float4*)f)[i];
        uint2 r; r.x = f2h2(v.x, v.y); r.y = f2h2(v.z, v.w);
        ((uint2*)fH)[i] = r;
    }
    if (vec_ok) {
        const int npair4 = npair >> 2;
        const int tot = K * npair4;
        for (int t = t0; t < tot; t += stride) {
            int k = t / npair4, i = t - k * npair4;
            int4 s4 = *(const int4*)(scatter + (size_t)k * npair + i * 4);
            if (s4.x < M) atomicAdd(&cnt[(s4.x >> 8) * K + k], 1);
            if (s4.y < M) atomicAdd(&cnt[(s4.y >> 8) * K + k], 1);
            if (s4.z < M) atomicAdd(&cnt[(s4.z >> 8) * K + k], 1);
            if (s4.w < M) atomicAdd(&cnt[(s4.w >> 8) * K + k], 1);
        }
    } else {
        const int tot = K * npair;
        for (int t = t0; t < tot; t += stride) {
            int k = t / npair, i = t - k * npair;
            int s = scatter[(size_t)k * npair + i];
            if (s < M) atomicAdd(&cnt[(s >> 8) * K + k], 1);
        }
    }
}

// ---- scan (3 phases) over cnt[0..n) -> exclusive bs, total at bs[n] ----
__global__ void sc1(const int* __restrict__ in, int* __restrict__ part, int n)
{
    __shared__ int red[256];
    int base = blockIdx.x * SCAN_B;
    int sum = 0;
    for (int i = threadIdx.x; i < SCAN_B; i += 256) {
        int idx = base + i;
        sum += (idx < n) ? in[idx] : 0;
    }
    red[threadIdx.x] = sum;
    __syncthreads();
    for (int s = 128; s > 0; s >>= 1) {
        if (threadIdx.x < s) red[threadIdx.x] += red[threadIdx.x + s];
        __syncthreads();
    }
    if (threadIdx.x == 0) part[blockIdx.x] = red[0];
}

__global__ void sc2(int* __restrict__ part, int nb, int* __restrict__ total_out)
{
    __shared__ int a[2048], b[2048];
    int t = threadIdx.x;
    for (int i = t; i < 2048; i += 1024) a[i] = (i < nb) ? part[i] : 0;
    __syncthreads();
    int* src = a; int* dst = b;
    for (int ofs = 1; ofs < 2048; ofs <<= 1) {
        for (int i = t; i < 2048; i += 1024)
            dst[i] = (i >= ofs) ? src[i] + src[i - ofs] : src[i];
        __syncthreads();
        int* tmp = src; src = dst; dst = tmp;
    }
    for (int i = t; i < 2048; i += 1024)
        if (i < nb) part[i] = (i == 0) ? 0 : src[i - 1];
    if (t == 0) *total_out = src[nb - 1];
}

__global__ void sc3(const int* __restrict__ in, const int* __restrict__ part,
                    int* __restrict__ outExcl, int n)
{
    __shared__ int ts[256];
    int base = blockIdx.x * SCAN_B;
    int v[8];
    int sum = 0;
#pragma unroll
    for (int j = 0; j < 8; ++j) {
        int idx = base + threadIdx.x * 8 + j;
        v[j] = (idx < n) ? in[idx] : 0;
        sum += v[j];
    }
    ts[threadIdx.x] = sum;
    __syncthreads();
    for (int ofs = 1; ofs < 256; ofs <<= 1) {
        int add = (threadIdx.x >= ofs) ? ts[threadIdx.x - ofs] : 0;
        __syncthreads();
        ts[threadIdx.x] += add;
        __syncthreads();
    }
    int excl = (threadIdx.x == 0) ? 0 : ts[threadIdx.x - 1];
    excl += part[blockIdx.x];
#pragma unroll
    for (int j = 0; j < 8; ++j) {
        int idx = base + threadIdx.x * 8 + j;
        if (idx < n) outExcl[idx] = excl;
        excl += v[j];
    }
}

// ---- scatter entries into (chunk,k) buckets: entry = (row_local<<18)|g ----
__global__ void kb_build2(const int* __restrict__ gather, const int* __restrict__ scatter,
                          const int* __restrict__ bs, int* __restrict__ cur,
                          int* __restrict__ list, int npair, int M, int K, int vec_ok)
{
    int k = blockIdx.y;
    const int* sp = scatter + (size_t)k * npair;
    const int* gp = gather  + (size_t)k * npair;
    int t = blockIdx.x * blockDim.x + threadIdx.x;
    if (vec_ok) {
        int base = t * 4;
        if (base >= npair) return;
        int4 s4 = *(const int4*)(sp + base);
        int4 g4 = *(const int4*)(gp + base);
        if (s4.x < M) { int b = (s4.x >> 8) * K + k;
            list[bs[b] + atomicAdd(&cur[b], 1)] = ((s4.x & 255) << 18) | g4.x; }
        if (s4.y < M) { int b = (s4.y >> 8) * K + k;
            list[bs[b] + atomicAdd(&cur[b], 1)] = ((s4.y & 255) << 18) | g4.y; }
        if (s4.z < M) { int b = (s4.z >> 8) * K + k;
            list[bs[b] + atomicAdd(&cur[b], 1)] = ((s4.z & 255) << 18) | g4.z; }
        if (s4.w < M) { int b = (s4.w >> 8) * K + k;
            list[bs[b] + atomicAdd(&cur[b], 1)] = ((s4.w & 255) << 18) | g4.w; }
    } else {
        if (t >= npair) return;
        int s = sp[t];
        if (s < M) { int b = (s >> 8) * K + k;
            list[bs[b] + atomicAdd(&cur[b], 1)] = ((s & 255) << 18) | gp[t]; }
    }
}

// ---- main: block per 256-row chunk. Wave w handles k = w, w+4, ...
//      Per 16 entries: 16-lane list load, per-lane 16B A-gather (lane = entry x
//      cin-block), 2x mfma_f32_16x16x32_f16 (B = prepacked W[k] fragments),
//      8x ds_add_f32 scatter into stride-33 LDS accumulator.
//      Invalid lanes -> sentinel row CH (junk). Write-once coalesced output. ----
__global__ __launch_bounds__(256)
void km_mfma(const uint4* __restrict__ fH4, const uint4* __restrict__ wFrag4,
             const int* __restrict__ bs, const int* __restrict__ list,
             float* __restrict__ out, int M, int K)
{
    __shared__ float acc[(CH + 1) * 33];            // 33924 B
    const int tid = threadIdx.x;
    const int c   = blockIdx.x;

    for (int i = tid; i < (CH + 1) * 33; i += 256) acc[i] = 0.f;
    __syncthreads();

    const int lane = tid & 63;
    const int wv   = tid >> 6;
    const int lo16 = lane & 15;
    const int hi4  = lane >> 4;

    for (int k = wv; k < K; k += 4) {
        const int bin = c * K + k;
        const int e0 = bs[bin], e1 = bs[bin + 1];
        if (e0 >= e1) continue;

        f16x8 B0 = __builtin_bit_cast(f16x8, wFrag4[(k * 2 + 0) * 64 + lane]);
        f16x8 B1 = __builtin_bit_cast(f16x8, wFrag4[(k * 2 + 1) * 64 + lane]);

        for (int e = e0; e < e1; e += 16) {
            int pk = (CH << 18);                    // sentinel -> junk row
            if (lane < 16 && e + lane < e1) pk = list[e + lane];
            int g = __shfl(pk, lo16, 64) & 0x3FFFF; // entry lo16's feature row
            f16x8 A = __builtin_bit_cast(f16x8, fH4[(size_t)g * 4 + hi4]);
            f32x4 z = {0.f, 0.f, 0.f, 0.f};
            f32x4 d0 = __builtin_amdgcn_mfma_f32_16x16x32_f16(A, B0, z, 0, 0, 0);
            f32x4 d1 = __builtin_amdgcn_mfma_f32_16x16x32_f16(A, B1, z, 0, 0, 0);
            const int ebase = hi4 << 2;
#pragma unroll
            for (int r = 0; r < 4; ++r) {
                int rle = __shfl(pk, ebase + r, 64) >> 18;
                atomicAdd(&acc[rle * 33 + lo16],      d0[r]);
                atomicAdd(&acc[rle * 33 + 16 + lo16], d1[r]);
            }
        }
    }
    __syncthreads();

    const int m0 = c * CH;
    int nrow = M - m0; if (nrow > CH) nrow = CH;
    for (int i = tid; i < nrow * 32; i += 256) {
        int r = i >> 5, o = i & 31;
        out[(size_t)(m0 + r) * 32 + o] = acc[r * 33 + o];
    }
}

// ---- fallback: atomic scatter (R1, proven) ----
__global__ __launch_bounds__(256, 4)
void spconv_scatter(const float* __restrict__ feat, const float* __restrict__ weight,
                    const int* __restrict__ gather, const int* __restrict__ scatter,
                    float* __restrict__ out, int npair, int M)
{
    const int k = blockIdx.y;
    const int lane = threadIdx.x & 31;
    const int sub = threadIdx.x >> 5;
    const int pairs_per_blk = blockDim.x >> 5;
    const float* wk = weight + (size_t)k * (CIN * COUT);
    float w[CIN];
#pragma unroll
    for (int i = 0; i < CIN; ++i) w[i] = wk[i * COUT + lane];
    const int* gk = gather + (size_t)k * npair;
    const int* sk = scatter + (size_t)k * npair;
    for (int p = blockIdx.x * pairs_per_blk + sub; p < npair; p += gridDim.x * pairs_per_blk) {
        int s = sk[p];
        if (s >= M) continue;
        int g = gk[p];
        const float4* fr = (const float4*)(feat + (size_t)g * CIN);
        float a = 0.f;
#pragma unroll
        for (int c = 0; c < 8; ++c) {
            float4 f4 = fr[c];
            a = fmaf(f4.x, w[4*c+0], a); a = fmaf(f4.y, w[4*c+1], a);
            a = fmaf(f4.z, w[4*c+2], a); a = fmaf(f4.w, w[4*c+3], a);
        }
        atomicAdd(&out[(size_t)s * COUT + lane], a);
    }
}

extern "C" void kernel_launch(void* const* d_in, const int* in_sizes, int n_in,
                              void* d_out, int out_size, void* d_ws, size_t ws_size,
                              hipStream_t stream)
{
    const float* feat    = (const float*)d_in[0];
    const float* weight  = (const float*)d_in[1];
    const int*   gather  = (const int*)d_in[2];
    const int*   scatter = (const int*)d_in[3];
    float*       out     = (float*)d_out;

    const int N     = in_sizes[0] / CIN;            // input sites (150000)
    const int K     = in_sizes[1] / (CIN * COUT);   // 27
    const int npair = in_sizes[2] / K;              // 150000
    const int M     = out_size / COUT;              // num_out (~2.13M)
    const int NC    = (M + CH - 1) / CH;            // chunks (~8333)
    const int NBIN  = NC * K;                       // bins (~225K)
    const int NB    = (NBIN + SCAN_B - 1) / SCAN_B; // scan blocks (~110)
    const int vec_ok = ((npair & 3) == 0) ? 1 : 0;

    uintptr_t base = (uintptr_t)d_ws;
    auto align256 = [](uintptr_t p) { return (p + 255) & ~(uintptr_t)255; };
    uintptr_t p_cnt  = align256(base);                              // NBIN ints
    uintptr_t p_cur  = align256(p_cnt + (size_t)NBIN * 4);          // NBIN ints
    uintptr_t p_bs   = align256(p_cur + (size_t)NBIN * 4);          // NBIN+1 ints
    uintptr_t p_part = align256(p_bs + ((size_t)NBIN + 1) * 4);     // 2048 ints
    uintptr_t p_wF   = align256(p_part + 2048 * 4);                 // K*512 uints
    uintptr_t p_fH   = align256(p_wF + (size_t)K * 512 * 4);        // N*16 uints
    uintptr_t p_list = align256(p_fH + (size_t)N * 16 * 4);         // K*npair ints
    uintptr_t p_end  = p_list + (size_t)K * npair * 4;

    if (p_end - base > ws_size || NB > 2048 || N > 0x3FFFF) {
        hipMemsetAsync(d_out, 0, (size_t)out_size * sizeof(float), stream);
        dim3 grid(160, K);
        spconv_scatter<<<grid, 256, 0, stream>>>(feat, weight, gather, scatter, out, npair, M);
        return;
    }

    int*      cnt  = (int*)p_cnt;
    int*      cur  = (int*)p_cur;
    int*      bs   = (int*)p_bs;
    int*      part = (int*)p_part;
    unsigned* wF   = (unsigned*)p_wF;
    unsigned* fH   = (unsigned*)p_fH;
    int*      list = (int*)p_list;

    // cnt and cur are adjacent -> zero both (cur starts aligned right after cnt)
    hipMemsetAsync(cnt, 0, (size_t)(p_bs - p_cnt), stream);

    k_prep2<<<2048, 256, 0, stream>>>(weight, feat, scatter, wF, fH, cnt,
                                      K, N, npair, M, vec_ok);

    sc1<<<NB, 256, 0, stream>>>(cnt, part, NBIN);
    sc2<<<1, 1024, 0, stream>>>(part, NB, bs + NBIN);
    sc3<<<NB, 256, 0, stream>>>(cnt, part, bs, NBIN);

    const int pthreads = vec_ok ? npair / 4 : npair;
    dim3 gp((pthreads + 255) / 256, K);
    kb_build2<<<gp, 256, 0, stream>>>(gather, scatter, bs, cur, list, npair, M, K, vec_ok);

    km_mfma<<<NC, 256, 0, stream>>>((const uint4*)fH, (const uint4*)wF,
                                    bs, list, out, M, K);
}

// Round 13
// 1077.412 us; speedup vs baseline: 1.2522x; 1.2522x over previous
//
#include <hip/hip_runtime.h>

#define CIN    32
#define COUT   32
#define KMAX   27
#define TILE   2048         // scan tile (256 thr x 8)

typedef _Float16 h2_t __attribute__((ext_vector_type(2)));

__device__ __forceinline__ float dot2(unsigned f, unsigned w, float a)
{
#if __has_builtin(__builtin_amdgcn_fdot2)
    return __builtin_amdgcn_fdot2(__builtin_bit_cast(h2_t, f),
                                  __builtin_bit_cast(h2_t, w), a, false);
#else
    h2_t ff = __builtin_bit_cast(h2_t, f), ww = __builtin_bit_cast(h2_t, w);
    return a + (float)ff.x * (float)ww.x + (float)ff.y * (float)ww.y;
#endif
}

__device__ __forceinline__ unsigned f2h2(float a, float b)
{
    unsigned short ua = __builtin_bit_cast(unsigned short, (_Float16)a);
    unsigned short ub = __builtin_bit_cast(unsigned short, (_Float16)b);
    return (unsigned)ua | ((unsigned)ub << 16);
}

// ---- D2: fused prep — pack W (R6 layout), pack feat, build per-row k-mask ----
__global__ void k_fuse(const float* __restrict__ w, const float* __restrict__ f,
                       const int* __restrict__ scatter,
                       unsigned* __restrict__ wH, unsigned* __restrict__ fH,
                       unsigned* __restrict__ mask,
                       int K, int N, int npair, int M, int vec_ok)
{
    const int t0 = blockIdx.x * blockDim.x + threadIdx.x;
    const int stride = gridDim.x * blockDim.x;

    // W pack: uint idx = ((k*4+j)*32+o)*4+dj holds cin (8j+2dj, 8j+2dj+1) for cout o
    for (int i = t0; i < K * 512; i += stride) {
        int dj = i & 3, o = (i >> 2) & 31, j = (i >> 7) & 3, k = i >> 9;
        int i0 = 8 * j + 2 * dj;
        wH[i] = f2h2(w[(k * CIN + i0) * COUT + o], w[(k * CIN + i0 + 1) * COUT + o]);
    }
    // feat pack: fH[g*16+c] = f16pair(feat[g][2c], feat[g][2c+1])
    for (int i = t0; i < N * 8; i += stride) {
        float4 v = ((const float4*)f)[i];
        uint2 r; r.x = f2h2(v.x, v.y); r.y = f2h2(v.z, v.w);
        ((uint2*)fH)[i] = r;
    }
    // mask: injective within k => 1 bit per (row,k)
    if (vec_ok) {
        const int npair4 = npair >> 2;
        const long long tot = (long long)K * npair4;
        for (long long t = t0; t < tot; t += stride) {
            int k = (int)(t / npair4), i = (int)(t - (long long)k * npair4);
            unsigned kb = 1u << k;
            int4 s4 = *(const int4*)(scatter + (size_t)k * npair + (size_t)i * 4);
            if (s4.x < M) atomicOr(&mask[s4.x], kb);
            if (s4.y < M) atomicOr(&mask[s4.y], kb);
            if (s4.z < M) atomicOr(&mask[s4.z], kb);
            if (s4.w < M) atomicOr(&mask[s4.w], kb);
        }
    } else {
        const long long tot = (long long)K * npair;
        for (long long t = t0; t < tot; t += stride) {
            int k = (int)(t / npair), i = (int)(t - (long long)k * npair);
            int s = scatter[(size_t)k * npair + i];
            if (s < M) atomicOr(&mask[s], 1u << k);
        }
    }
}

// ---- D3: single-pass decoupled-lookback exclusive scan of popc(mask) ----
// state[tile] u64: [63:62]=status (0 invalid, 1 aggregate, 2 prefix), [31:0]=value
#define ST_AGG  (1ull << 62)
#define ST_PRE  (2ull << 62)
__global__ __launch_bounds__(256)
void scan_lb(const unsigned* __restrict__ mask, unsigned long long* __restrict__ state,
             int* __restrict__ row_start, int n)
{
    __shared__ int ts[256];
    __shared__ int sBase;
    const int tile = blockIdx.x;
    const int tid  = threadIdx.x;
    const int base = tile * TILE;

    int v[8];
    int sum = 0;
#pragma unroll
    for (int j = 0; j < 8; ++j) {
        int idx = base + tid * 8 + j;
        v[j] = (idx < n) ? __popc(mask[idx]) : 0;
        sum += v[j];
    }
    ts[tid] = sum;
    __syncthreads();
    for (int ofs = 1; ofs < 256; ofs <<= 1) {
        int add = (tid >= ofs) ? ts[tid - ofs] : 0;
        __syncthreads();
        ts[tid] += add;
        __syncthreads();
    }
    const int agg = ts[255];

    if (tid == 0) {
        if (tile == 0) {
            __hip_atomic_store(&state[0], ST_PRE | (unsigned)agg,
                               __ATOMIC_RELEASE, __HIP_MEMORY_SCOPE_AGENT);
            sBase = 0;
        } else {
            __hip_atomic_store(&state[tile], ST_AGG | (unsigned)agg,
                               __ATOMIC_RELEASE, __HIP_MEMORY_SCOPE_AGENT);
            // lookback
            long long acc = 0;
            int t = tile - 1;
            for (;;) {
                unsigned long long st = __hip_atomic_load(&state[t],
                                            __ATOMIC_ACQUIRE, __HIP_MEMORY_SCOPE_AGENT);
                unsigned long long status = st >> 62;
                if (status == 0) continue;                 // not yet published
                acc += (unsigned)(st & 0xFFFFFFFFull);
                if (status == 2) break;                    // found prefix
                --t;
            }
            __hip_atomic_store(&state[tile], ST_PRE | (unsigned)(acc + agg),
                               __ATOMIC_RELEASE, __HIP_MEMORY_SCOPE_AGENT);
            sBase = (int)acc;
        }
    }
    __syncthreads();

    int excl = sBase + ((tid == 0) ? 0 : ts[tid - 1]);
#pragma unroll
    for (int j = 0; j < 8; ++j) {
        int idx = base + tid * 8 + j;
        if (idx < n) row_start[idx] = excl;
        excl += v[j];
    }
    if (tile == gridDim.x - 1 && tid == 255) row_start[n] = sBase + agg;
}

// ---- D4: build CSR entries, slot deterministic (k-ascending within row) ----
__global__ void kb_build(const int* __restrict__ gather, const int* __restrict__ scatter,
                         const unsigned* __restrict__ mask, const int* __restrict__ row_start,
                         int* __restrict__ list, int npair, int M, int vec_ok)
{
    int k = blockIdx.y;
    const int* sp = scatter + (size_t)k * npair;
    const int* gp = gather  + (size_t)k * npair;
    unsigned klow = (1u << k) - 1u;
    int t = blockIdx.x * blockDim.x + threadIdx.x;
    if (vec_ok) {
        int base = t * 4;
        if (base >= npair) return;
        int4 s4 = *(const int4*)(sp + base);
        int4 g4 = *(const int4*)(gp + base);
        if (s4.x < M) list[row_start[s4.x] + __popc(mask[s4.x] & klow)] = (k << 18) | g4.x;
        if (s4.y < M) list[row_start[s4.y] + __popc(mask[s4.y] & klow)] = (k << 18) | g4.y;
        if (s4.z < M) list[row_start[s4.z] + __popc(mask[s4.z] & klow)] = (k << 18) | g4.z;
        if (s4.w < M) list[row_start[s4.w] + __popc(mask[s4.w] & klow)] = (k << 18) | g4.w;
    } else {
        if (t >= npair) return;
        int s = sp[t];
        if (s < M) list[row_start[s] + __popc(mask[s] & klow)] = (k << 18) | gp[t];
    }
}

// ---- D5: main (R6 verbatim: weights in LDS, f16 dot2, half-wave per row) ----
__global__ __launch_bounds__(1024, 8)
void kb_main(const uint4* __restrict__ featH, const uint4* __restrict__ wH,
             const int* __restrict__ row_start, const int* __restrict__ list,
             float* __restrict__ out, int M, int K)
{
    __shared__ uint4 wL[KMAX * 128];                 // 55296 B
    for (int i = threadIdx.x; i < K * 128; i += 1024) wL[i] = wH[i];
    __syncthreads();

    const int lane = threadIdx.x & 31;               // output channel
    int h  = (blockIdx.x * 1024 + threadIdx.x) >> 5;
    int nh = (gridDim.x * 1024) >> 5;
    for (int m = h; m < M; m += nh) {
        int e0 = row_start[m], e1 = row_start[m + 1];
        float a0 = 0.f, a1 = 0.f, a2 = 0.f, a3 = 0.f;
        for (int e = e0; e < e1; ++e) {
            int pk = list[e];
            int k = pk >> 18, g = pk & 0x3FFFF;
            const uint4* fr = featH + ((size_t)g << 2);
            uint4 f0 = fr[0], f1 = fr[1], f2 = fr[2], f3 = fr[3];   // broadcast
            const uint4* wr = wL + k * 128 + lane;
            uint4 w0 = wr[0], w1 = wr[32], w2 = wr[64], w3 = wr[96];
            a0 = dot2(f0.x, w0.x, a0); a0 = dot2(f0.y, w0.y, a0);
            a0 = dot2(f0.z, w0.z, a0); a0 = dot2(f0.w, w0.w, a0);
            a1 = dot2(f1.x, w1.x, a1); a1 = dot2(f1.y, w1.y, a1);
            a1 = dot2(f1.z, w1.z, a1); a1 = dot2(f1.w, w1.w, a1);
            a2 = dot2(f2.x, w2.x, a2); a2 = dot2(f2.y, w2.y, a2);
            a2 = dot2(f2.z, w2.z, a2); a2 = dot2(f2.w, w2.w, a2);
            a3 = dot2(f3.x, w3.x, a3); a3 = dot2(f3.y, w3.y, a3);
            a3 = dot2(f3.z, w3.z, a3); a3 = dot2(f3.w, w3.w, a3);
        }
        out[(size_t)m * COUT + lane] = (a0 + a1) + (a2 + a3);
    }
}

// ---- fallback: atomic scatter (R1, proven) ----
__global__ __launch_bounds__(256, 4)
void spconv_scatter(const float* __restrict__ feat, const float* __restrict__ weight,
                    const int* __restrict__ gather, const int* __restrict__ scatter,
                    float* __restrict__ out, int npair, int M)
{
    const int k = blockIdx.y;
    const int lane = threadIdx.x & 31;
    const int sub = threadIdx.x >> 5;
    const int pairs_per_blk = blockDim.x >> 5;
    const float* wk = weight + (size_t)k * (CIN * COUT);
    float w[CIN];
#pragma unroll
    for (int i = 0; i < CIN; ++i) w[i] = wk[i * COUT + lane];
    const int* gk = gather + (size_t)k * npair;
    const int* sk = scatter + (size_t)k * npair;
    for (int p = blockIdx.x * pairs_per_blk + sub; p < npair; p += gridDim.x * pairs_per_blk) {
        int s = sk[p];
        if (s >= M) continue;
        int g = gk[p];
        const float4* fr = (const float4*)(feat + (size_t)g * CIN);
        float a = 0.f;
#pragma unroll
        for (int c = 0; c < 8; ++c) {
            float4 f4 = fr[c];
            a = fmaf(f4.x, w[4*c+0], a); a = fmaf(f4.y, w[4*c+1], a);
            a = fmaf(f4.z, w[4*c+2], a); a = fmaf(f4.w, w[4*c+3], a);
        }
        atomicAdd(&out[(size_t)s * COUT + lane], a);
    }
}

extern "C" void kernel_launch(void* const* d_in, const int* in_sizes, int n_in,
                              void* d_out, int out_size, void* d_ws, size_t ws_size,
                              hipStream_t stream)
{
    const float* feat    = (const float*)d_in[0];
    const float* weight  = (const float*)d_in[1];
    const int*   gather  = (const int*)d_in[2];
    const int*   scatter = (const int*)d_in[3];
    float*       out     = (float*)d_out;

    const int N     = in_sizes[0] / CIN;            // input sites (150000)
    const int K     = in_sizes[1] / (CIN * COUT);   // 27
    const int npair = in_sizes[2] / K;              // 150000
    const int M     = out_size / COUT;              // num_out (~2.13M)
    const int NT    = (M + TILE - 1) / TILE;        // scan tiles (~1041)
    const int vec_ok = ((npair & 3) == 0) ? 1 : 0;

    // workspace: state | mask | row_start | wH | fH | list
    uintptr_t base = (uintptr_t)d_ws;
    auto align256 = [](uintptr_t p) { return (p + 255) & ~(uintptr_t)255; };
    uintptr_t p_state = align256(base);                            // NT u64
    uintptr_t p_mask  = align256(p_state + (size_t)NT * 8);        // M uints
    uintptr_t p_rs    = align256(p_mask + (size_t)M * 4);          // M+1 ints
    uintptr_t p_wH    = align256(p_rs + ((size_t)M + 1) * 4);      // K*512 uints
    uintptr_t p_fH    = align256(p_wH + (size_t)K * 512 * 4);      // N*16 uints
    uintptr_t p_list  = align256(p_fH + (size_t)N * 16 * 4);       // K*npair ints
    uintptr_t p_end   = p_list + (size_t)K * npair * 4;

    if (p_end - base > ws_size || K > KMAX || N > 0x40000) {
        hipMemsetAsync(d_out, 0, (size_t)out_size * sizeof(float), stream);
        dim3 grid(160, K);
        spconv_scatter<<<grid, 256, 0, stream>>>(feat, weight, gather, scatter, out, npair, M);
        return;
    }

    unsigned long long* state = (unsigned long long*)p_state;
    unsigned* mask      = (unsigned*)p_mask;
    int*      row_start = (int*)p_rs;
    unsigned* wH        = (unsigned*)p_wH;
    unsigned* fH        = (unsigned*)p_fH;
    int*      list      = (int*)p_list;

    // D1: one memset covers scan state + mask (contiguous region)
    hipMemsetAsync((void*)p_state, 0, (size_t)(p_rs - p_state), stream);

    // D2: fused pack + mask
    k_fuse<<<2048, 256, 0, stream>>>(weight, feat, scatter, wH, fH, mask,
                                     K, N, npair, M, vec_ok);

    // D3: single-pass scan -> row_start[0..M]
    scan_lb<<<NT, 256, 0, stream>>>(mask, state, row_start, M);

    // D4: build CSR list
    const int pthreads = vec_ok ? npair / 4 : npair;
    dim3 gp((pthreads + 255) / 256, K);
    kb_build<<<gp, 256, 0, stream>>>(gather, scatter, mask, row_start, list,
                                     npair, M, vec_ok);

    // D5: main (write-once, no memset of d_out)
    kb_main<<<512, 1024, 0, stream>>>((const uint4*)fH, (const uint4*)wH,
                                      row_start, list, out, M, K);
}

// Round 14
// 710.244 us; speedup vs baseline: 1.8996x; 1.5170x over previous
//
#include <hip/hip_runtime.h>

#define CIN    32
#define COUT   32
#define KMAX   27
#define SCAN_B 2048

typedef _Float16 h2_t __attribute__((ext_vector_type(2)));

__device__ __forceinline__ float dot2(unsigned f, unsigned w, float a)
{
#if __has_builtin(__builtin_amdgcn_fdot2)
    return __builtin_amdgcn_fdot2(__builtin_bit_cast(h2_t, f),
                                  __builtin_bit_cast(h2_t, w), a, false);
#else
    h2_t ff = __builtin_bit_cast(h2_t, f), ww = __builtin_bit_cast(h2_t, w);
    return a + (float)ff.x * (float)ww.x + (float)ff.y * (float)ww.y;
#endif
}

__device__ __forceinline__ unsigned f2h2(float a, float b)
{
    unsigned short ua = __builtin_bit_cast(unsigned short, (_Float16)a);
    unsigned short ub = __builtin_bit_cast(unsigned short, (_Float16)b);
    return (unsigned)ua | ((unsigned)ub << 16);
}

// ---- fused prep: pack W (R6 layout), pack feat, build per-row k-mask ----
__global__ void k_fuse(const float* __restrict__ w, const float* __restrict__ f,
                       const int* __restrict__ scatter,
                       unsigned* __restrict__ wH, unsigned* __restrict__ fH,
                       unsigned* __restrict__ mask,
                       int K, int N, int npair, int M, int vec_ok)
{
    const int t0 = blockIdx.x * blockDim.x + threadIdx.x;
    const int stride = gridDim.x * blockDim.x;

    for (int i = t0; i < K * 512; i += stride) {
        int dj = i & 3, o = (i >> 2) & 31, j = (i >> 7) & 3, k = i >> 9;
        int i0 = 8 * j + 2 * dj;
        wH[i] = f2h2(w[(k * CIN + i0) * COUT + o], w[(k * CIN + i0 + 1) * COUT + o]);
    }
    for (int i = t0; i < N * 8; i += stride) {
        float4 v = ((const float4*)f)[i];
        uint2 r; r.x = f2h2(v.x, v.y); r.y = f2h2(v.z, v.w);
        ((uint2*)fH)[i] = r;
    }
    if (vec_ok) {
        const int npair4 = npair >> 2;
        const long long tot = (long long)K * npair4;
        for (long long t = t0; t < tot; t += stride) {
            int k = (int)(t / npair4), i = (int)(t - (long long)k * npair4);
            unsigned kb = 1u << k;
            int4 s4 = *(const int4*)(scatter + (size_t)k * npair + (size_t)i * 4);
            if (s4.x < M) atomicOr(&mask[s4.x], kb);
            if (s4.y < M) atomicOr(&mask[s4.y], kb);
            if (s4.z < M) atomicOr(&mask[s4.z], kb);
            if (s4.w < M) atomicOr(&mask[s4.w], kb);
        }
    } else {
        const long long tot = (long long)K * npair;
        for (long long t = t0; t < tot; t += stride) {
            int k = (int)(t / npair), i = (int)(t - (long long)k * npair);
            int s = scatter[(size_t)k * npair + i];
            if (s < M) atomicOr(&mask[s], 1u << k);
        }
    }
}

// ---- scan level 1: per-block sums of popcount(mask) ----
__global__ void kb_scan1(const unsigned* __restrict__ mask, int* __restrict__ part, int n)
{
    __shared__ int red[256];
    int base = blockIdx.x * SCAN_B;
    int sum = 0;
    for (int i = threadIdx.x; i < SCAN_B; i += 256) {
        int idx = base + i;
        sum += (idx < n) ? __popc(mask[idx]) : 0;
    }
    red[threadIdx.x] = sum;
    __syncthreads();
    for (int s = 128; s > 0; s >>= 1) {
        if (threadIdx.x < s) red[threadIdx.x] += red[threadIdx.x + s];
        __syncthreads();
    }
    if (threadIdx.x == 0) part[blockIdx.x] = red[0];
}

// ---- scan level 2: single-block exclusive scan of part[0..nb), nb<=2048 ----
__global__ void kb_scan2(int* __restrict__ part, int nb, int* __restrict__ total_out)
{
    __shared__ int a[2048], b[2048];
    int t = threadIdx.x;
    for (int i = t; i < 2048; i += 1024) a[i] = (i < nb) ? part[i] : 0;
    __syncthreads();
    int* src = a; int* dst = b;
    for (int ofs = 1; ofs < 2048; ofs <<= 1) {
        for (int i = t; i < 2048; i += 1024)
            dst[i] = (i >= ofs) ? src[i] + src[i - ofs] : src[i];
        __syncthreads();
        int* tmp = src; src = dst; dst = tmp;
    }
    for (int i = t; i < 2048; i += 1024)
        if (i < nb) part[i] = (i == 0) ? 0 : src[i - 1];
    if (t == 0) *total_out = src[nb - 1];
}

// ---- scan level 3: block-local exclusive scan + block offset ----
__global__ void kb_scan3(const unsigned* __restrict__ mask, const int* __restrict__ part,
                         int* __restrict__ row_start, int n)
{
    __shared__ int ts[256];
    int base = blockIdx.x * SCAN_B;
    int v[8];
    int sum = 0;
#pragma unroll
    for (int j = 0; j < 8; ++j) {
        int idx = base + threadIdx.x * 8 + j;
        v[j] = (idx < n) ? __popc(mask[idx]) : 0;
        sum += v[j];
    }
    ts[threadIdx.x] = sum;
    __syncthreads();
    for (int ofs = 1; ofs < 256; ofs <<= 1) {
        int add = (threadIdx.x >= ofs) ? ts[threadIdx.x - ofs] : 0;
        __syncthreads();
        ts[threadIdx.x] += add;
        __syncthreads();
    }
    int excl = (threadIdx.x == 0) ? 0 : ts[threadIdx.x - 1];
    excl += part[blockIdx.x];
#pragma unroll
    for (int j = 0; j < 8; ++j) {
        int idx = base + threadIdx.x * 8 + j;
        if (idx < n) row_start[idx] = excl;
        excl += v[j];
    }
}

// ---- build CSR entries, slot deterministic (k-ascending within row) ----
__global__ void kb_build(const int* __restrict__ gather, const int* __restrict__ scatter,
                         const unsigned* __restrict__ mask, const int* __restrict__ row_start,
                         int* __restrict__ list, int npair, int M, int vec_ok)
{
    int k = blockIdx.y;
    const int* sp = scatter + (size_t)k * npair;
    const int* gp = gather  + (size_t)k * npair;
    unsigned klow = (1u << k) - 1u;
    int t = blockIdx.x * blockDim.x + threadIdx.x;
    if (vec_ok) {
        int base = t * 4;
        if (base >= npair) return;
        int4 s4 = *(const int4*)(sp + base);
        int4 g4 = *(const int4*)(gp + base);
        if (s4.x < M) list[row_start[s4.x] + __popc(mask[s4.x] & klow)] = (k << 18) | g4.x;
        if (s4.y < M) list[row_start[s4.y] + __popc(mask[s4.y] & klow)] = (k << 18) | g4.y;
        if (s4.z < M) list[row_start[s4.z] + __popc(mask[s4.z] & klow)] = (k << 18) | g4.z;
        if (s4.w < M) list[row_start[s4.w] + __popc(mask[s4.w] & klow)] = (k << 18) | g4.w;
    } else {
        if (t >= npair) return;
        int s = sp[t];
        if (s < M) list[row_start[s] + __popc(mask[s] & klow)] = (k << 18) | gp[t];
    }
}

// ---- main (R6 champion verbatim): weights in LDS, f16 dot2, half-wave per row ----
__global__ __launch_bounds__(1024, 8)
void kb_main(const uint4* __restrict__ featH, const uint4* __restrict__ wH,
             const int* __restrict__ row_start, const int* __restrict__ list,
             float* __restrict__ out, int M, int K)
{
    __shared__ uint4 wL[KMAX * 128];                 // 55296 B
    for (int i = threadIdx.x; i < K * 128; i += 1024) wL[i] = wH[i];
    __syncthreads();

    const int lane = threadIdx.x & 31;               // output channel
    int h  = (blockIdx.x * 1024 + threadIdx.x) >> 5;
    int nh = (gridDim.x * 1024) >> 5;
    for (int m = h; m < M; m += nh) {
        int e0 = row_start[m], e1 = row_start[m + 1];
        float a0 = 0.f, a1 = 0.f, a2 = 0.f, a3 = 0.f;
        for (int e = e0; e < e1; ++e) {
            int pk = list[e];
            int k = pk >> 18, g = pk & 0x3FFFF;
            const uint4* fr = featH + ((size_t)g << 2);
            uint4 f0 = fr[0], f1 = fr[1], f2 = fr[2], f3 = fr[3];   // broadcast
            const uint4* wr = wL + k * 128 + lane;
            uint4 w0 = wr[0], w1 = wr[32], w2 = wr[64], w3 = wr[96];
            a0 = dot2(f0.x, w0.x, a0); a0 = dot2(f0.y, w0.y, a0);
            a0 = dot2(f0.z, w0.z, a0); a0 = dot2(f0.w, w0.w, a0);
            a1 = dot2(f1.x, w1.x, a1); a1 = dot2(f1.y, w1.y, a1);
            a1 = dot2(f1.z, w1.z, a1); a1 = dot2(f1.w, w1.w, a1);
            a2 = dot2(f2.x, w2.x, a2); a2 = dot2(f2.y, w2.y, a2);
            a2 = dot2(f2.z, w2.z, a2); a2 = dot2(f2.w, w2.w, a2);
            a3 = dot2(f3.x, w3.x, a3); a3 = dot2(f3.y, w3.y, a3);
            a3 = dot2(f3.z, w3.z, a3); a3 = dot2(f3.w, w3.w, a3);
        }
        out[(size_t)m * COUT + lane] = (a0 + a1) + (a2 + a3);
    }
}

// ---- fallback: atomic scatter (R1, proven) ----
__global__ __launch_bounds__(256, 4)
void spconv_scatter(const float* __restrict__ feat, const float* __restrict__ weight,
                    const int* __restrict__ gather, const int* __restrict__ scatter,
                    float* __restrict__ out, int npair, int M)
{
    const int k = blockIdx.y;
    const int lane = threadIdx.x & 31;
    const int sub = threadIdx.x >> 5;
    const int pairs_per_blk = blockDim.x >> 5;
    const float* wk = weight + (size_t)k * (CIN * COUT);
    float w[CIN];
#pragma unroll
    for (int i = 0; i < CIN; ++i) w[i] = wk[i * COUT + lane];
    const int* gk = gather + (size_t)k * npair;
    const int* sk = scatter + (size_t)k * npair;
    for (int p = blockIdx.x * pairs_per_blk + sub; p < npair; p += gridDim.x * pairs_per_blk) {
        int s = sk[p];
        if (s >= M) continue;
        int g = gk[p];
        const float4* fr = (const float4*)(feat + (size_t)g * CIN);
        float a = 0.f;
#pragma unroll
        for (int c = 0; c < 8; ++c) {
            float4 f4 = fr[c];
            a = fmaf(f4.x, w[4*c+0], a); a = fmaf(f4.y, w[4*c+1], a);
            a = fmaf(f4.z, w[4*c+2], a); a = fmaf(f4.w, w[4*c+3], a);
        }
        atomicAdd(&out[(size_t)s * COUT + lane], a);
    }
}

extern "C" void kernel_launch(void* const* d_in, const int* in_sizes, int n_in,
                              void* d_out, int out_size, void* d_ws, size_t ws_size,
                              hipStream_t stream)
{
    const float* feat    = (const float*)d_in[0];
    const float* weight  = (const float*)d_in[1];
    const int*   gather  = (const int*)d_in[2];
    const int*   scatter = (const int*)d_in[3];
    float*       out     = (float*)d_out;

    const int N     = in_sizes[0] / CIN;            // input sites (150000)
    const int K     = in_sizes[1] / (CIN * COUT);   // 27
    const int npair = in_sizes[2] / K;              // 150000
    const int M     = out_size / COUT;              // num_out (~2.13M)
    const int NB    = (M + SCAN_B - 1) / SCAN_B;    // scan blocks (~1041)
    const int vec_ok = ((npair & 3) == 0) ? 1 : 0;

    // workspace: mask | row_start | part | wH | fH | list
    uintptr_t base = (uintptr_t)d_ws;
    auto align256 = [](uintptr_t p) { return (p + 255) & ~(uintptr_t)255; };
    uintptr_t p_mask = align256(base);                             // M uints
    uintptr_t p_rs   = align256(p_mask + (size_t)M * 4);           // M+1 ints
    uintptr_t p_part = align256(p_rs + ((size_t)M + 1) * 4);       // 2048 ints
    uintptr_t p_wH   = align256(p_part + 2048 * 4);                // K*512 uints
    uintptr_t p_fH   = align256(p_wH + (size_t)K * 512 * 4);       // N*16 uints
    uintptr_t p_list = align256(p_fH + (size_t)N * 16 * 4);        // K*npair ints
    uintptr_t p_end  = p_list + (size_t)K * npair * 4;

    if (p_end - base > ws_size || NB > 2048 || K > KMAX || N > 0x40000) {
        hipMemsetAsync(d_out, 0, (size_t)out_size * sizeof(float), stream);
        dim3 grid(160, K);
        spconv_scatter<<<grid, 256, 0, stream>>>(feat, weight, gather, scatter, out, npair, M);
        return;
    }

    unsigned* mask      = (unsigned*)p_mask;
    int*      row_start = (int*)p_rs;
    int*      part      = (int*)p_part;
    unsigned* wH        = (unsigned*)p_wH;
    unsigned* fH        = (unsigned*)p_fH;
    int*      list      = (int*)p_list;

    hipMemsetAsync(mask, 0, (size_t)M * 4, stream);

    // fused pack + mask
    k_fuse<<<2048, 256, 0, stream>>>(weight, feat, scatter, wH, fH, mask,
                                     K, N, npair, M, vec_ok);

    // proven 3-phase scan -> row_start[0..M]
    kb_scan1<<<NB, 256, 0, stream>>>(mask, part, M);
    kb_scan2<<<1, 1024, 0, stream>>>(part, NB, row_start + M);
    kb_scan3<<<NB, 256, 0, stream>>>(mask, part, row_start, M);

    // build CSR list
    const int pthreads = vec_ok ? npair / 4 : npair;
    dim3 gp((pthreads + 255) / 256, K);
    kb_build<<<gp, 256, 0, stream>>>(gather, scatter, mask, row_start, list,
                                     npair, M, vec_ok);

    // main (write-once, no memset of d_out)
    kb_main<<<512, 1024, 0, stream>>>((const uint4*)fH, (const uint4*)wH,
                                      row_start, list, out, M, K);
}